// Round 3
// baseline (647.878 us; speedup 1.0000x reference)
//
#include <hip/hip_runtime.h>
#include <math.h>

typedef _Float16 f16;
typedef _Float16 f16x8 __attribute__((ext_vector_type(8)));
typedef float f32x4 __attribute__((ext_vector_type(4)));

#define DIM 1024

__device__ __forceinline__ float phi_f(float x) {
  return x > 0.f ? x + 1.f : __expf(x);  // elu(x)+1
}

// global -> LDS direct DMA, 16 B per lane. lds base must be wave-uniform.
typedef __attribute__((address_space(1))) const void gconst_t;
typedef __attribute__((address_space(3))) void lds_t;
__device__ __forceinline__ void g2l16(const void* g, void* l) {
  __builtin_amdgcn_global_load_lds((gconst_t*)(uintptr_t)g, (lds_t*)(uintptr_t)l, 16, 0, 0);
}

// ---------------- fp32 -> fp16 convert (weights) ----------------
__global__ __launch_bounds__(256) void cvt_f32_f16(const float* __restrict__ src,
                                                   f16* __restrict__ dst) {
  int i = (blockIdx.x * 256 + threadIdx.x) * 4;
  float4 v = *(const float4*)(src + i);
  union { f16 h[4]; uint2 u; } p;
  p.h[0] = (f16)v.x; p.h[1] = (f16)v.y; p.h[2] = (f16)v.z; p.h[3] = (f16)v.w;
  *(uint2*)(dst + i) = p.u;
}

// ---------------- fused K/V projection + partial KV ----------------
// Block = (head h, s-tile st of 128 rows). Computes K-tile=phi(key@Wk^T+bk)*mask,
// V-tile=value@Wv^T+bv, then partial P[e][d] = sum_s V[s,e]*K[s,d] and
// partial Ksum[d] = sum_s K[s,d]. Partials -> pP/pKs, reduced later.
#define PADW 144  // f16 elems per padded row (288 B, 16B-aligned, breaks bank conflicts)
__global__ __launch_bounds__(256) void proj_kv(const float* __restrict__ key,
                                               const float* __restrict__ value,
                                               const f16* __restrict__ Wkh,
                                               const f16* __restrict__ Wvh,
                                               const float* __restrict__ bk,
                                               const float* __restrict__ bv,
                                               const int* __restrict__ mask,
                                               float* __restrict__ pP,
                                               float* __restrict__ pKs) {
  __shared__ __attribute__((aligned(16))) char smem[40960];
  float* Af = (float*)smem;             // [128][64] fp32 staging (32 KB)
  f16* Bf = (f16*)(smem + 32768);       // [64][64] f16 weight slice (8 KB)
  f16* KT = (f16*)smem;                 // [64][PADW] epilogue overlay (18 KB)
  f16* VT = (f16*)(smem + 18432);       // [64][PADW] (18 KB)

  const int tid = threadIdx.x;
  const int lane = tid & 63;
  const int l15 = lane & 15, l4 = lane >> 4;
  const int w = tid >> 6;
  const int h = blockIdx.x;             // 16
  const int st = blockIdx.y;            // 128 s-tiles of 128 rows
  const int row0 = st * 128;
  const int n0 = h * 64;

  f32x4 acc_k[2][4], acc_v[2][4];
#pragma unroll
  for (int j = 0; j < 4; j++) {
    float bkv = bk[n0 + j * 16 + l15];
    float bvv = bv[n0 + j * 16 + l15];
#pragma unroll
    for (int i = 0; i < 2; i++) {
      acc_k[i][j] = (f32x4){bkv, bkv, bkv, bkv};
      acc_v[i][j] = (f32x4){bvv, bvv, bvv, bvv};
    }
  }

  for (int kt = 0; kt < DIM; kt += 64) {
#pragma unroll
    for (int pass = 0; pass < 2; pass++) {
      const float* A = pass ? value : key;
      const f16* W = pass ? Wvh : Wkh;
      __syncthreads();
      // stage A fp32 [128][64]: 8 DMA calls/wave
#pragma unroll
      for (int c = 0; c < 8; c++) {
        int row = w * 32 + c * 4 + (lane >> 4);
        int col = (lane & 15) * 4;
        g2l16(A + (size_t)(row0 + row) * DIM + kt + col, (char*)Af + w * 8192 + c * 1024);
      }
      // stage W f16 [64][64]: 2 DMA calls/wave
#pragma unroll
      for (int c = 0; c < 2; c++) {
        int row = w * 16 + c * 8 + (lane >> 3);
        int col = (lane & 7) * 8;
        g2l16(W + (size_t)(n0 + row) * DIM + kt + col, (char*)Bf + w * 2048 + c * 1024);
      }
      __syncthreads();
#pragma unroll
      for (int ks = 0; ks < 2; ks++) {
        f16x8 af[2], bfr[4];
#pragma unroll
        for (int i = 0; i < 2; i++) {
          const float* ap = &Af[(size_t)(w * 32 + i * 16 + l15) * 64 + ks * 32 + l4 * 8];
          float4 x0 = *(const float4*)ap;
          float4 x1 = *(const float4*)(ap + 4);
          f16x8 a;
          a[0] = (f16)x0.x; a[1] = (f16)x0.y; a[2] = (f16)x0.z; a[3] = (f16)x0.w;
          a[4] = (f16)x1.x; a[5] = (f16)x1.y; a[6] = (f16)x1.z; a[7] = (f16)x1.w;
          af[i] = a;
        }
#pragma unroll
        for (int j = 0; j < 4; j++)
          bfr[j] = *(f16x8*)&Bf[(size_t)(j * 16 + l15) * 64 + ks * 32 + l4 * 8];
        if (pass == 0) {
#pragma unroll
          for (int i = 0; i < 2; i++)
#pragma unroll
            for (int j = 0; j < 4; j++)
              acc_k[i][j] = __builtin_amdgcn_mfma_f32_16x16x32_f16(af[i], bfr[j], acc_k[i][j], 0, 0, 0);
        } else {
#pragma unroll
          for (int i = 0; i < 2; i++)
#pragma unroll
            for (int j = 0; j < 4; j++)
              acc_v[i][j] = __builtin_amdgcn_mfma_f32_16x16x32_f16(af[i], bfr[j], acc_v[i][j], 0, 0, 0);
        }
      }
    }
  }

  // ---- epilogue: phi+mask, transpose both tiles into LDS ----
  __syncthreads();
#pragma unroll
  for (int i = 0; i < 2; i++)
#pragma unroll
    for (int j = 0; j < 4; j++)
#pragma unroll
      for (int r = 0; r < 4; r++) {
        int s_loc = w * 32 + i * 16 + l4 * 4 + r;
        int dcol = j * 16 + l15;
        float kx = acc_k[i][j][r];
        kx = phi_f(kx);
        if (mask[row0 + s_loc] == 0) kx = 0.f;
        KT[dcol * PADW + s_loc] = (f16)kx;
        VT[dcol * PADW + s_loc] = (f16)acc_v[i][j][r];
      }
  __syncthreads();

  // ---- partial P[e][d] = sum_s VT[e][s] * KT[d][s] (MFMA, K-dim = s = 128) ----
  f32x4 accp[4];
#pragma unroll
  for (int j = 0; j < 4; j++) accp[j] = (f32x4){0.f, 0.f, 0.f, 0.f};
#pragma unroll
  for (int ks = 0; ks < 4; ks++) {
    f16x8 af = *(f16x8*)&VT[(size_t)(w * 16 + l15) * PADW + ks * 32 + l4 * 8];
#pragma unroll
    for (int j = 0; j < 4; j++) {
      f16x8 bfr = *(f16x8*)&KT[(size_t)(j * 16 + l15) * PADW + ks * 32 + l4 * 8];
      accp[j] = __builtin_amdgcn_mfma_f32_16x16x32_f16(af, bfr, accp[j], 0, 0, 0);
    }
  }
  const size_t blk = (size_t)h * 128 + st;
#pragma unroll
  for (int j = 0; j < 4; j++)
#pragma unroll
    for (int r = 0; r < 4; r++) {
      int e = w * 16 + l4 * 4 + r;
      pP[blk * 4096 + (size_t)e * 64 + j * 16 + l15] = accp[j][r];
    }
  // ---- partial Ksum[d] = sum_s KT[d][s] ----
  if (tid < 64) {
    float s = 0.f;
#pragma unroll
    for (int c = 0; c < 16; c++) {
      f16x8 v = *(f16x8*)&KT[tid * PADW + c * 8];
#pragma unroll
      for (int q = 0; q < 8; q++) s += (float)v[q];
    }
    pKs[blk * 64 + tid] = s;
  }
}

// ---------------- reduce partials -> KVT (f16, [bh][e][d]) + Ksum(+eps) ----------------
__global__ __launch_bounds__(256) void kv_reduce(const float* __restrict__ pP,
                                                 const float* __restrict__ pKs,
                                                 f16* __restrict__ KVT,
                                                 float* __restrict__ Ksum) {
  const int bh = blockIdx.x;  // 64
  const int b = bh >> 4, h = bh & 15;
  const int tid = threadIdx.x;
  for (int cell = tid; cell < 4096; cell += 256) {
    float s = 0.f;
#pragma unroll
    for (int c = 0; c < 32; c++) s += pP[(size_t)(h * 128 + b * 32 + c) * 4096 + cell];
    KVT[(size_t)bh * 4096 + cell] = (f16)s;
  }
  if (tid < 64) {
    float s = 0.f;
#pragma unroll
    for (int c = 0; c < 32; c++) s += pKs[(size_t)(h * 128 + b * 32 + c) * 64 + tid];
    Ksum[bh * 64 + tid] = s + 1e-6f;  // EPS folded in
  }
}

// ---------------- fused Q-projection -> phi -> Z -> V_new = Z * (phi(q) . KV) ----------------
__global__ __launch_bounds__(256) void gemm_q_vnew(const float* __restrict__ Aq,
                                                   const f16* __restrict__ Wqh,
                                                   const float* __restrict__ bq,
                                                   const f16* __restrict__ KVT,
                                                   const float* __restrict__ Ksum,
                                                   f16* __restrict__ Vnew) {
  __shared__ __attribute__((aligned(16))) char smem[32768 + 16384 + 1024 + 512];
  f16 (*As)[64] = (f16(*)[64])smem;                   // [128][64], phase 1
  f16 (*Bs)[64] = (f16(*)[64])(smem + 16384);         // [128][64], phase 1 (DMA)
  f16 (*Ph)[128] = (f16(*)[128])smem;                 // [128][128], overlays As+Bs
  f16* KVTs = (f16*)(smem + 32768);                   // [2][64][64]
  float* Zlds = (float*)(smem + 32768 + 16384);       // [2][128]
  float* KsumS = (float*)(smem + 32768 + 16384 + 1024);  // [128]

  const int tid = threadIdx.x;
  const int lane = tid & 63;
  const int l15 = lane & 15, l4 = lane >> 4;
  const int w = tid >> 6, wr = w >> 1, wc = w & 1;
  const int nb = blockIdx.x;      // 0..7
  const int n0 = nb * 128;
  const int m0 = blockIdx.y * 128;
  const int b = m0 >> 12;
  const int bh0 = b * 16 + nb * 2;

#pragma unroll
  for (int r = 0; r < 4; r++) {
    int e = r * 2048 + tid * 8;
    *(uint4*)(KVTs + e) = *(const uint4*)(KVT + (size_t)bh0 * 4096 + e);
  }
  if (tid < 128) KsumS[tid] = Ksum[bh0 * 64 + tid];

  // ---- phase 1: q = query @ Wq^T + bq ----
  f32x4 acc[4][4];
#pragma unroll
  for (int j = 0; j < 4; j++) {
    float bvv = bq[n0 + wc * 64 + j * 16 + l15];
#pragma unroll
    for (int i = 0; i < 4; i++) acc[i][j] = (f32x4){bvv, bvv, bvv, bvv};
  }
  for (int kt = 0; kt < DIM; kt += 64) {
    __syncthreads();
    // B via DMA (f16 weights)
#pragma unroll
    for (int c = 0; c < 4; c++) {
      int row = w * 32 + c * 8 + (lane >> 3);
      int col = (lane & 7) * 8;
      g2l16(Wqh + (size_t)(n0 + row) * DIM + kt + col, (char*)Bs + w * 4096 + c * 1024);
    }
    // A via reg-staging + cvt (fp32 source)
#pragma unroll
    for (int r = 0; r < 8; r++) {
      int e = r * 1024 + tid * 4;
      int row = e >> 6, col = e & 63;
      float4 va = *(const float4*)(Aq + (size_t)(m0 + row) * DIM + kt + col);
      union { f16 hh[4]; uint2 u; } pa;
      pa.hh[0] = (f16)va.x; pa.hh[1] = (f16)va.y; pa.hh[2] = (f16)va.z; pa.hh[3] = (f16)va.w;
      *(uint2*)&As[row][col] = pa.u;
    }
    __syncthreads();
#pragma unroll
    for (int ks = 0; ks < 2; ks++) {
      f16x8 af[4], bfr[4];
#pragma unroll
      for (int i = 0; i < 4; i++)
        af[i] = *(f16x8*)&As[wr * 64 + i * 16 + l15][ks * 32 + l4 * 8];
#pragma unroll
      for (int j = 0; j < 4; j++)
        bfr[j] = *(f16x8*)&Bs[wc * 64 + j * 16 + l15][ks * 32 + l4 * 8];
#pragma unroll
      for (int i = 0; i < 4; i++)
#pragma unroll
        for (int j = 0; j < 4; j++)
          acc[i][j] = __builtin_amdgcn_mfma_f32_16x16x32_f16(af[i], bfr[j], acc[i][j], 0, 0, 0);
    }
  }

  // ---- phi + stash to LDS ----
  __syncthreads();
#pragma unroll
  for (int i = 0; i < 4; i++)
#pragma unroll
    for (int j = 0; j < 4; j++)
#pragma unroll
      for (int r = 0; r < 4; r++) {
        int row = wr * 64 + i * 16 + l4 * 4 + r;
        int col = wc * 64 + j * 16 + l15;
        Ph[row][col] = (f16)phi_f(acc[i][j][r]);
      }
  __syncthreads();

  // ---- Z per row/head ----
  if (tid < 128) {
    float den0 = 0.f, den1 = 0.f;
    for (int c = 0; c < 64; c += 8) {
      f16x8 p0 = *(f16x8*)&Ph[tid][c];
      f16x8 p1 = *(f16x8*)&Ph[tid][64 + c];
#pragma unroll
      for (int q = 0; q < 8; q++) {
        den0 += (float)p0[q] * KsumS[c + q];
        den1 += (float)p1[q] * KsumS[64 + c + q];
      }
    }
    Zlds[tid] = 1.f / den0;
    Zlds[128 + tid] = 1.f / den1;
  }
  __syncthreads();

  // ---- phase 2: V_new = Z * (phi(q) @ KV) per head ----
  f32x4 a2[4][4];
#pragma unroll
  for (int i = 0; i < 4; i++)
#pragma unroll
    for (int j = 0; j < 4; j++) a2[i][j] = (f32x4){0.f, 0.f, 0.f, 0.f};
#pragma unroll
  for (int ks = 0; ks < 2; ks++) {
    f16x8 af[4], bfr[4];
#pragma unroll
    for (int i = 0; i < 4; i++)
      af[i] = *(f16x8*)&Ph[wr * 64 + i * 16 + l15][wc * 64 + ks * 32 + l4 * 8];
#pragma unroll
    for (int j = 0; j < 4; j++)
      bfr[j] = *(f16x8*)&KVTs[wc * 4096 + (j * 16 + l15) * 64 + ks * 32 + l4 * 8];
#pragma unroll
    for (int i = 0; i < 4; i++)
#pragma unroll
      for (int j = 0; j < 4; j++)
        a2[i][j] = __builtin_amdgcn_mfma_f32_16x16x32_f16(af[i], bfr[j], a2[i][j], 0, 0, 0);
  }
#pragma unroll
  for (int i = 0; i < 4; i++)
#pragma unroll
    for (int j = 0; j < 4; j++)
#pragma unroll
      for (int r = 0; r < 4; r++) {
        int row = wr * 64 + i * 16 + l4 * 4 + r;
        float zv = Zlds[wc * 128 + row];
        int gn = n0 + wc * 64 + j * 16 + l15;
        Vnew[(size_t)(m0 + row) * DIM + gn] = (f16)(a2[i][j][r] * zv);
      }
}

// ---------------- O-GEMM: out = Vnew @ Wo^T + bo (f16 x f16 -> f32) ----------------
__global__ __launch_bounds__(256) void gemm_o(const f16* __restrict__ A,
                                              const f16* __restrict__ Woh,
                                              const float* __restrict__ bo,
                                              float* __restrict__ Out) {
  __shared__ __attribute__((aligned(16))) f16 As[128][64];
  __shared__ __attribute__((aligned(16))) f16 Bs[128][64];
  const int tid = threadIdx.x;
  const int lane = tid & 63;
  const int l15 = lane & 15, l4 = lane >> 4;
  const int w = tid >> 6, wr = w >> 1, wc = w & 1;
  const int n0 = blockIdx.x * 128;
  const int m0 = blockIdx.y * 128;

  f32x4 acc[4][4];
#pragma unroll
  for (int j = 0; j < 4; j++) {
    float bvv = bo[n0 + wc * 64 + j * 16 + l15];
#pragma unroll
    for (int i = 0; i < 4; i++) acc[i][j] = (f32x4){bvv, bvv, bvv, bvv};
  }

  for (int kt = 0; kt < DIM; kt += 64) {
    __syncthreads();
#pragma unroll
    for (int c = 0; c < 4; c++) {
      int row = w * 32 + c * 8 + (lane >> 3);
      int col = (lane & 7) * 8;
      g2l16(A + (size_t)(m0 + row) * DIM + kt + col, (char*)As + w * 4096 + c * 1024);
      g2l16(Woh + (size_t)(n0 + row) * DIM + kt + col, (char*)Bs + w * 4096 + c * 1024);
    }
    __syncthreads();
#pragma unroll
    for (int ks = 0; ks < 2; ks++) {
      f16x8 af[4], bfr[4];
#pragma unroll
      for (int i = 0; i < 4; i++)
        af[i] = *(f16x8*)&As[wr * 64 + i * 16 + l15][ks * 32 + l4 * 8];
#pragma unroll
      for (int j = 0; j < 4; j++)
        bfr[j] = *(f16x8*)&Bs[wc * 64 + j * 16 + l15][ks * 32 + l4 * 8];
#pragma unroll
      for (int i = 0; i < 4; i++)
#pragma unroll
        for (int j = 0; j < 4; j++)
          acc[i][j] = __builtin_amdgcn_mfma_f32_16x16x32_f16(af[i], bfr[j], acc[i][j], 0, 0, 0);
    }
  }

#pragma unroll
  for (int i = 0; i < 4; i++)
#pragma unroll
    for (int j = 0; j < 4; j++) {
      const int rl = wr * 64 + i * 16 + l4 * 4;
      const int gn = n0 + wc * 64 + j * 16 + l15;
#pragma unroll
      for (int r = 0; r < 4; r++)
        Out[(size_t)(m0 + rl + r) * DIM + gn] = acc[i][j][r];
    }
}

extern "C" void kernel_launch(void* const* d_in, const int* in_sizes, int n_in,
                              void* d_out, int out_size, void* d_ws, size_t ws_size,
                              hipStream_t stream) {
  (void)in_sizes; (void)n_in; (void)out_size; (void)ws_size;
  const float* query = (const float*)d_in[0];
  const float* key = (const float*)d_in[1];
  const float* value = (const float*)d_in[2];
  const int* kmask = (const int*)d_in[3];
  const float* Wq = (const float*)d_in[4];
  const float* bq = (const float*)d_in[5];
  const float* Wk = (const float*)d_in[6];
  const float* bk = (const float*)d_in[7];
  const float* Wv = (const float*)d_in[8];
  const float* bv = (const float*)d_in[9];
  const float* Wo = (const float*)d_in[10];
  const float* bo = (const float*)d_in[11];

  // workspace layout (peak ~37 MiB)
  char* ws = (char*)d_ws;
  f16* W0 = (f16*)ws;                                  // 2 MiB: Wkh, later Wqh
  f16* W1 = (f16*)(ws + ((size_t)2 << 20));            // 2 MiB: Wvh, later Woh
  float* pP = (float*)(ws + ((size_t)4 << 20));        // 2048*4096*4 = 32 MiB
  float* pKs = (float*)(ws + ((size_t)36 << 20));      // 2048*64*4 = 512 KiB
  f16* KVT = (f16*)(ws + ((size_t)36 << 20) + ((size_t)512 << 10));   // 512 KiB
  float* Ksum = (float*)(ws + ((size_t)37 << 20));     // 16 KiB
  f16* Vnew = (f16*)pP;  // overlays pP (dead after kv_reduce), 32 MiB

  dim3 blk(256);
  cvt_f32_f16<<<1024, blk, 0, stream>>>(Wk, W0);
  cvt_f32_f16<<<1024, blk, 0, stream>>>(Wv, W1);
  proj_kv<<<dim3(16, 128), blk, 0, stream>>>(key, value, W0, W1, bk, bv, kmask, pP, pKs);
  kv_reduce<<<64, blk, 0, stream>>>(pP, pKs, KVT, Ksum);
  cvt_f32_f16<<<1024, blk, 0, stream>>>(Wq, W0);
  cvt_f32_f16<<<1024, blk, 0, stream>>>(Wo, W1);
  gemm_q_vnew<<<dim3(8, 128), blk, 0, stream>>>(query, W0, bq, KVT, Ksum, Vnew);
  gemm_o<<<dim3(8, 128), blk, 0, stream>>>(Vnew, W1, bo, (float*)d_out);
}